// Round 18
// baseline (110.102 us; speedup 1.0000x reference)
//
#include <hip/hip_runtime.h>
#include <hip/hip_bf16.h>

#define BB 128
#define TT 1024
#define ENC_DIM 512
#define QUERY_DIM 1024
#define ATT_DIM 128
#define ATT_FILTERS 32
#define ATT_KERNEL 31
#define TILE_T 64
#define NTILE (TT / TILE_T)   // 16

using f32x4 = __attribute__((ext_vector_type(4))) float;
using f32x2 = __attribute__((ext_vector_type(2))) float;

__device__ __forceinline__ float tanh_fast(float x) {
    float e = __expf(2.0f * x);
    return 1.0f - 2.0f * __builtin_amdgcn_rcpf(1.0f + e);
}

// K1: pq partials. grid (B, 2).
__global__ __launch_bounds__(256) void k_pq(const float* __restrict__ query,
                                            const float* __restrict__ Wq,
                                            float* __restrict__ pqp) {
    __shared__ float q[512];
    __shared__ float pp[128];
    int b = blockIdx.x, h = blockIdx.y;
    int tid = threadIdx.x, a = tid & 127, ks = tid >> 7;
    for (int i = tid; i < 512; i += 256) q[i] = query[b * QUERY_DIM + h * 512 + i];
    __syncthreads();
    const float* w  = Wq + (h * 512 + ks * 256) * ATT_DIM + a;
    const float* qs = q + ks * 256;
    float acc = 0.f;
#pragma unroll 16
    for (int k = 0; k < 256; ++k) acc += qs[k] * w[k * ATT_DIM];
    if (ks) pp[a] = acc;
    __syncthreads();
    if (!ks) pqp[(h * BB + b) * ATT_DIM + a] = acc + pp[a];
}

// K2: fused energies + max-free chunk softmax + context partials.
// grid (NTILE, B). R16 + pm register prefetch hoisted ahead of conv.
__global__ __launch_bounds__(256, 4) void k_fused(
    const float* __restrict__ aw,    // (B,T,2)
    const float* __restrict__ ck,    // (31,2,32)
    const float* __restrict__ Wloc,  // (32,128)
    const float* __restrict__ pm,    // (B,T,128)
    const float* __restrict__ pqp,   // (2,B,128)
    const float* __restrict__ v,     // (128)
    const float* __restrict__ mem,   // (B,T,ENC)
    float* __restrict__ energies,    // (B,T) ws
    float* __restrict__ partP,       // (NTILE,B,ENC) ws
    float* __restrict__ partS)       // (NTILE,B) ws: chunk exp-sums
{
    __shared__ float s_aw[(TILE_T + 30) * 2];
    __shared__ float s_ck[ATT_KERNEL * 2 * ATT_FILTERS];
    __shared__ float s_f[TILE_T * ATT_FILTERS];
    __shared__ float s_e[TILE_T];
    __shared__ float s_w[TILE_T];
    __shared__ f32x4 sr[ENC_DIM / 4];

    int s = blockIdx.x, b = blockIdx.y;
    int t0 = s * TILE_T;
    int tid = threadIdx.x;

    // ---- stage conv weights + aw halo ----
    for (int i = tid; i < ATT_KERNEL * 2 * ATT_FILTERS; i += 256) s_ck[i] = ck[i];
    for (int i = tid; i < (TILE_T + 30) * 2; i += 256) {
        int ii = i >> 1, c = i & 1;
        int t = t0 - 15 + ii;
        s_aw[i] = (t >= 0 && t < TT) ? aw[(b * TT + t) * 2 + c] : 0.f;
    }
    __syncthreads();

    // ---- pm prefetch: all 16 pairs issued here, consumed after conv ----
    int w = tid >> 6, lane = tid & 63;
    int a = lane * 2;
    const float* pmb = pm + ((long)(b * TT + t0)) * ATT_DIM + a;
    float2 c00 = *reinterpret_cast<const float2*>(&pmb[(w)      * ATT_DIM]);
    float2 c01 = *reinterpret_cast<const float2*>(&pmb[(w + 4)  * ATT_DIM]);
    float2 c02 = *reinterpret_cast<const float2*>(&pmb[(w + 8)  * ATT_DIM]);
    float2 c03 = *reinterpret_cast<const float2*>(&pmb[(w + 12) * ATT_DIM]);
    float2 c10 = *reinterpret_cast<const float2*>(&pmb[(w + 16) * ATT_DIM]);
    float2 c11 = *reinterpret_cast<const float2*>(&pmb[(w + 20) * ATT_DIM]);
    float2 c12 = *reinterpret_cast<const float2*>(&pmb[(w + 24) * ATT_DIM]);
    float2 c13 = *reinterpret_cast<const float2*>(&pmb[(w + 28) * ATT_DIM]);
    float2 c20 = *reinterpret_cast<const float2*>(&pmb[(w + 32) * ATT_DIM]);
    float2 c21 = *reinterpret_cast<const float2*>(&pmb[(w + 36) * ATT_DIM]);
    float2 c22 = *reinterpret_cast<const float2*>(&pmb[(w + 40) * ATT_DIM]);
    float2 c23 = *reinterpret_cast<const float2*>(&pmb[(w + 44) * ATT_DIM]);
    float2 c30 = *reinterpret_cast<const float2*>(&pmb[(w + 48) * ATT_DIM]);
    float2 c31 = *reinterpret_cast<const float2*>(&pmb[(w + 52) * ATT_DIM]);
    float2 c32 = *reinterpret_cast<const float2*>(&pmb[(w + 56) * ATT_DIM]);
    float2 c33 = *reinterpret_cast<const float2*>(&pmb[(w + 60) * ATT_DIM]);

    {   // conv: filter j per thread, weights register-cached
        int j = tid & 31;
        float wk0[ATT_KERNEL], wk1[ATT_KERNEL];
#pragma unroll
        for (int k = 0; k < ATT_KERNEL; ++k) {
            wk0[k] = s_ck[k * 64 + j];
            wk1[k] = s_ck[k * 64 + 32 + j];
        }
        for (int t = tid >> 5; t < TILE_T; t += 8) {
            float acc0 = 0.f, acc1 = 0.f;
#pragma unroll
            for (int k = 0; k < ATT_KERNEL; ++k) {
                float2 awp = *reinterpret_cast<const float2*>(&s_aw[(t + k) * 2]);
                acc0 += awp.x * wk0[k];
                acc1 += awp.y * wk1[k];
            }
            s_f[t * ATT_FILTERS + j] = acc0 + acc1;
        }
    }
    __syncthreads();

    {
        float2 wl[ATT_FILTERS];
#pragma unroll
        for (int j = 0; j < ATT_FILTERS; ++j)
            wl[j] = *reinterpret_cast<const float2*>(&Wloc[j * ATT_DIM + a]);
        float2 pqA = *reinterpret_cast<const float2*>(&pqp[b * ATT_DIM + a]);
        float2 pqB = *reinterpret_cast<const float2*>(&pqp[(BB + b) * ATT_DIM + a]);
        float pq0 = pqA.x + pqB.x, pq1 = pqA.y + pqB.y;
        float2 vv = *reinterpret_cast<const float2*>(&v[a]);

        auto process = [&](int t, float2 c) {
            float x0 = pq0 + c.x;
            float x1 = pq1 + c.y;
            const float4* f4 = reinterpret_cast<const float4*>(&s_f[t * ATT_FILTERS]);
#pragma unroll
            for (int j4 = 0; j4 < ATT_FILTERS / 4; ++j4) {
                float4 f = f4[j4];
                x0 += f.x * wl[4 * j4].x     + f.y * wl[4 * j4 + 1].x
                    + f.z * wl[4 * j4 + 2].x + f.w * wl[4 * j4 + 3].x;
                x1 += f.x * wl[4 * j4].y     + f.y * wl[4 * j4 + 1].y
                    + f.z * wl[4 * j4 + 2].y + f.w * wl[4 * j4 + 3].y;
            }
            float e = tanh_fast(x0) * vv.x + tanh_fast(x1) * vv.y;
#pragma unroll
            for (int off = 32; off > 0; off >>= 1) e += __shfl_xor(e, off);
            if (lane == 0) {
                s_e[t] = e;
                energies[b * TT + t0 + t] = e;
            }
        };

        process(w,      c00); process(w + 4,  c01); process(w + 8,  c02); process(w + 12, c03);
        process(w + 16, c10); process(w + 20, c11); process(w + 24, c12); process(w + 28, c13);
        process(w + 32, c20); process(w + 36, c21); process(w + 40, c22); process(w + 44, c23);
        process(w + 48, c30); process(w + 52, c31); process(w + 56, c32); process(w + 60, c33);
    }
    __syncthreads();

    // ---- Phase B: max-free chunk softmax (|e| <= ~9, exp is f32-safe) ----
    float ex = 0.f;
    if (tid < TILE_T) {
        ex = __expf(s_e[tid]);
        s_w[tid] = ex;
    }
    __syncthreads();
    if (tid < 64) {   // wave 0: parallel sum of the 64 chunk exps (from register)
        float ss = ex;
#pragma unroll
        for (int off = 32; off > 0; off >>= 1) ss += __shfl_xor(ss, off);
        if (tid == 0) partS[s * BB + b] = ss;
    }

    // ---- Phase C: stream this block's memory chunk (NT loads, permanent) ----
    int p = tid >> 7, q = tid & 127;
    const f32x4* m4 = reinterpret_cast<const f32x4*>(mem + ((long)(b * TT + t0)) * ENC_DIM) + q;
    f32x4 acc = {0.f, 0.f, 0.f, 0.f};
#pragma unroll 16
    for (int t = p; t < TILE_T; t += 2) {
        float wt = s_w[t];
        f32x4 mv = __builtin_nontemporal_load(&m4[(long)t * (ENC_DIM / 4)]);
        acc += wt * mv;
    }
    __syncthreads();
    if (p == 1) sr[q] = acc;
    __syncthreads();
    if (p == 0) {
        acc += sr[q];
        reinterpret_cast<f32x4*>(partP)[(s * BB + b) * (ENC_DIM / 4) + q] = acc;
    }
}

// K3: combine partials -> ctx, wts. grid (B). Single pass: S = sum of partS.
__global__ __launch_bounds__(256) void k_final(
    const float* __restrict__ energies, // (B,T)
    const float* __restrict__ partP,    // (NTILE,B,ENC)
    const float* __restrict__ partS,    // (NTILE,B)
    float* __restrict__ wts,            // (B,T) out
    float* __restrict__ ctx)            // (B,ENC) out
{
    int b = blockIdx.x;
    int tid = threadIdx.x;

    float S = 0.f;
#pragma unroll
    for (int i = 0; i < NTILE; ++i) S += partS[i * BB + b];
    float invS = 1.0f / S;

    {   // weights: 1024 per row, 4 per thread
        float4 e = reinterpret_cast<const float4*>(energies + b * TT)[tid];
        float4 w;
        w.x = __expf(e.x) * invS;
        w.y = __expf(e.y) * invS;
        w.z = __expf(e.z) * invS;
        w.w = __expf(e.w) * invS;
        reinterpret_cast<float4*>(wts + b * TT)[tid] = w;
    }
    {   // context: 512 per row, 2 per thread
        f32x2 acc2 = {0.f, 0.f};
#pragma unroll
        for (int i = 0; i < NTILE; ++i) {
            f32x2 pv = *reinterpret_cast<const f32x2*>(&partP[((long)(i * BB + b)) * ENC_DIM + 2 * tid]);
            acc2 += pv;
        }
        acc2 *= invS;
        *reinterpret_cast<f32x2*>(&ctx[b * ENC_DIM + 2 * tid]) = acc2;
    }
}

extern "C" void kernel_launch(void* const* d_in, const int* in_sizes, int n_in,
                              void* d_out, int out_size, void* d_ws, size_t ws_size,
                              hipStream_t stream) {
    const float* query  = (const float*)d_in[0];
    const float* memory = (const float*)d_in[1];
    const float* pm     = (const float*)d_in[2];
    const float* awc    = (const float*)d_in[3];
    const float* Wq     = (const float*)d_in[4];
    const float* ck     = (const float*)d_in[5];
    const float* Wloc   = (const float*)d_in[6];
    const float* v      = (const float*)d_in[7];

    float* out = (float*)d_out;
    float* ctx = out;                       // (B, ENC_DIM)
    float* wts = out + BB * ENC_DIM;        // (B, T)

    float* pqp      = (float*)d_ws;                        // (2,B,128)
    float* energies = pqp + 2 * BB * ATT_DIM;              // (B,T)
    float* partP    = energies + BB * TT;                  // (NTILE,B,ENC)
    float* partS    = partP + (long)NTILE * BB * ENC_DIM;  // (NTILE,B)

    k_pq   <<<dim3(BB, 2),     dim3(256), 0, stream>>>(query, Wq, pqp);
    k_fused<<<dim3(NTILE, BB), dim3(256), 0, stream>>>(awc, ck, Wloc, pm, pqp, v,
                                                       memory, energies, partP, partS);
    k_final<<<dim3(BB),        dim3(256), 0, stream>>>(energies, partP, partS, wts, ctx);
}

// Round 19
// 94.165 us; speedup vs baseline: 1.1692x; 1.1692x over previous
//
#include <hip/hip_runtime.h>
#include <hip/hip_bf16.h>

#define BB 128
#define TT 1024
#define ENC_DIM 512
#define QUERY_DIM 1024
#define ATT_DIM 128
#define ATT_FILTERS 32
#define ATT_KERNEL 31
#define TILE_T 64
#define NTILE (TT / TILE_T)   // 16

using f32x4 = __attribute__((ext_vector_type(4))) float;
using f32x2 = __attribute__((ext_vector_type(2))) float;

__device__ __forceinline__ float tanh_fast(float x) {
    float e = __expf(2.0f * x);
    return 1.0f - 2.0f * __builtin_amdgcn_rcpf(1.0f + e);
}

// K1: pq partials. grid (B, 2).
__global__ __launch_bounds__(256) void k_pq(const float* __restrict__ query,
                                            const float* __restrict__ Wq,
                                            float* __restrict__ pqp) {
    __shared__ float q[512];
    __shared__ float pp[128];
    int b = blockIdx.x, h = blockIdx.y;
    int tid = threadIdx.x, a = tid & 127, ks = tid >> 7;
    for (int i = tid; i < 512; i += 256) q[i] = query[b * QUERY_DIM + h * 512 + i];
    __syncthreads();
    const float* w  = Wq + (h * 512 + ks * 256) * ATT_DIM + a;
    const float* qs = q + ks * 256;
    float acc = 0.f;
#pragma unroll 16
    for (int k = 0; k < 256; ++k) acc += qs[k] * w[k * ATT_DIM];
    if (ks) pp[a] = acc;
    __syncthreads();
    if (!ks) pqp[(h * BB + b) * ATT_DIM + a] = acc + pp[a];
}

// K2: fused energies (+inline exp, per-wave sums) + context partials.
// grid (NTILE, B). R16 minus phase B and minus the sr reduction.
__global__ __launch_bounds__(256, 4) void k_fused(
    const float* __restrict__ aw,    // (B,T,2)
    const float* __restrict__ ck,    // (31,2,32)
    const float* __restrict__ Wloc,  // (32,128)
    const float* __restrict__ pm,    // (B,T,128)
    const float* __restrict__ pqp,   // (2,B,128)
    const float* __restrict__ v,     // (128)
    const float* __restrict__ mem,   // (B,T,ENC)
    float* __restrict__ energies,    // (B,T) ws
    float* __restrict__ partP,       // (2*NTILE,B,ENC) ws: per half-block
    float* __restrict__ partS)       // (4*NTILE,B) ws: per-wave exp-sums
{
    __shared__ float s_aw[(TILE_T + 30) * 2];
    __shared__ float s_ck[ATT_KERNEL * 2 * ATT_FILTERS];
    __shared__ float s_f[TILE_T * ATT_FILTERS];
    __shared__ float s_w[TILE_T];

    int s = blockIdx.x, b = blockIdx.y;
    int t0 = s * TILE_T;
    int tid = threadIdx.x;

    // ---- stage conv weights + aw halo ----
    for (int i = tid; i < ATT_KERNEL * 2 * ATT_FILTERS; i += 256) s_ck[i] = ck[i];
    for (int i = tid; i < (TILE_T + 30) * 2; i += 256) {
        int ii = i >> 1, c = i & 1;
        int t = t0 - 15 + ii;
        s_aw[i] = (t >= 0 && t < TT) ? aw[(b * TT + t) * 2 + c] : 0.f;
    }
    __syncthreads();

    {   // conv: filter j per thread, weights register-cached
        int j = tid & 31;
        float wk0[ATT_KERNEL], wk1[ATT_KERNEL];
#pragma unroll
        for (int k = 0; k < ATT_KERNEL; ++k) {
            wk0[k] = s_ck[k * 64 + j];
            wk1[k] = s_ck[k * 64 + 32 + j];
        }
        for (int t = tid >> 5; t < TILE_T; t += 8) {
            float acc0 = 0.f, acc1 = 0.f;
#pragma unroll
            for (int k = 0; k < ATT_KERNEL; ++k) {
                float2 awp = *reinterpret_cast<const float2*>(&s_aw[(t + k) * 2]);
                acc0 += awp.x * wk0[k];
                acc1 += awp.y * wk1[k];
            }
            s_f[t * ATT_FILTERS + j] = acc0 + acc1;
        }
    }
    __syncthreads();

    {   // energies + inline exp + per-wave exp-sum
        int w = tid >> 6, lane = tid & 63;
        int a = lane * 2;
        float2 wl[ATT_FILTERS];
#pragma unroll
        for (int j = 0; j < ATT_FILTERS; ++j)
            wl[j] = *reinterpret_cast<const float2*>(&Wloc[j * ATT_DIM + a]);
        float2 pqA = *reinterpret_cast<const float2*>(&pqp[b * ATT_DIM + a]);
        float2 pqB = *reinterpret_cast<const float2*>(&pqp[(BB + b) * ATT_DIM + a]);
        float pq0 = pqA.x + pqB.x, pq1 = pqA.y + pqB.y;
        float2 vv = *reinterpret_cast<const float2*>(&v[a]);
        const float* pmb = pm + ((long)(b * TT + t0)) * ATT_DIM + a;

        float sumexp = 0.f;
        auto process = [&](int t, float2 c) {
            float x0 = pq0 + c.x;
            float x1 = pq1 + c.y;
            const float4* f4 = reinterpret_cast<const float4*>(&s_f[t * ATT_FILTERS]);
#pragma unroll
            for (int j4 = 0; j4 < ATT_FILTERS / 4; ++j4) {
                float4 f = f4[j4];
                x0 += f.x * wl[4 * j4].x     + f.y * wl[4 * j4 + 1].x
                    + f.z * wl[4 * j4 + 2].x + f.w * wl[4 * j4 + 3].x;
                x1 += f.x * wl[4 * j4].y     + f.y * wl[4 * j4 + 1].y
                    + f.z * wl[4 * j4 + 2].y + f.w * wl[4 * j4 + 3].y;
            }
            float e = tanh_fast(x0) * vv.x + tanh_fast(x1) * vv.y;
#pragma unroll
            for (int off = 32; off > 0; off >>= 1) e += __shfl_xor(e, off);
            float ex = __expf(e);
            sumexp += ex;
            if (lane == 0) {
                s_w[t] = ex;
                energies[b * TT + t0 + t] = e;
            }
        };

#pragma unroll
        for (int g = 0; g < 4; ++g) {   // 4 rows in flight; 4 groups x 16 t = 64
            int tg = w + g * 16;
            float2 c0 = *reinterpret_cast<const float2*>(&pmb[(tg)      * ATT_DIM]);
            float2 c1 = *reinterpret_cast<const float2*>(&pmb[(tg + 4)  * ATT_DIM]);
            float2 c2 = *reinterpret_cast<const float2*>(&pmb[(tg + 8)  * ATT_DIM]);
            float2 c3 = *reinterpret_cast<const float2*>(&pmb[(tg + 12) * ATT_DIM]);
            process(tg, c0);
            process(tg + 4, c1);
            process(tg + 8, c2);
            process(tg + 12, c3);
        }
        if (lane == 0) partS[(s * 4 + w) * BB + b] = sumexp;
    }
    __syncthreads();

    // ---- Phase C: stream memory chunk (NT); each half-block owns a partP slot ----
    int p = tid >> 7, q = tid & 127;
    const f32x4* m4 = reinterpret_cast<const f32x4*>(mem + ((long)(b * TT + t0)) * ENC_DIM) + q;
    f32x4 acc = {0.f, 0.f, 0.f, 0.f};
#pragma unroll 16
    for (int t = p; t < TILE_T; t += 2) {
        float wt = s_w[t];
        f32x4 mv = __builtin_nontemporal_load(&m4[(long)t * (ENC_DIM / 4)]);
        acc += wt * mv;
    }
    reinterpret_cast<f32x4*>(partP)[((s * 2 + p) * BB + b) * (ENC_DIM / 4) + q] = acc;
}

// K3: combine partials -> ctx, wts. grid (B).
__global__ __launch_bounds__(256) void k_final(
    const float* __restrict__ energies, // (B,T)
    const float* __restrict__ partP,    // (2*NTILE,B,ENC)
    const float* __restrict__ partS,    // (4*NTILE,B)
    float* __restrict__ wts,            // (B,T) out
    float* __restrict__ ctx)            // (B,ENC) out
{
    int b = blockIdx.x;
    int tid = threadIdx.x;

    float S = 0.f;
#pragma unroll
    for (int i = 0; i < 4 * NTILE; ++i) S += partS[i * BB + b];
    float invS = 1.0f / S;

    {   // weights: 1024 per row, 4 per thread
        float4 e = reinterpret_cast<const float4*>(energies + b * TT)[tid];
        float4 w;
        w.x = __expf(e.x) * invS;
        w.y = __expf(e.y) * invS;
        w.z = __expf(e.z) * invS;
        w.w = __expf(e.w) * invS;
        reinterpret_cast<float4*>(wts + b * TT)[tid] = w;
    }
    {   // context: 512 per row, 2 per thread
        f32x2 acc2 = {0.f, 0.f};
#pragma unroll
        for (int i = 0; i < 2 * NTILE; ++i) {
            f32x2 pv = *reinterpret_cast<const f32x2*>(&partP[((long)(i * BB + b)) * ENC_DIM + 2 * tid]);
            acc2 += pv;
        }
        acc2 *= invS;
        *reinterpret_cast<f32x2*>(&ctx[b * ENC_DIM + 2 * tid]) = acc2;
    }
}

extern "C" void kernel_launch(void* const* d_in, const int* in_sizes, int n_in,
                              void* d_out, int out_size, void* d_ws, size_t ws_size,
                              hipStream_t stream) {
    const float* query  = (const float*)d_in[0];
    const float* memory = (const float*)d_in[1];
    const float* pm     = (const float*)d_in[2];
    const float* awc    = (const float*)d_in[3];
    const float* Wq     = (const float*)d_in[4];
    const float* ck     = (const float*)d_in[5];
    const float* Wloc   = (const float*)d_in[6];
    const float* v      = (const float*)d_in[7];

    float* out = (float*)d_out;
    float* ctx = out;                       // (B, ENC_DIM)
    float* wts = out + BB * ENC_DIM;        // (B, T)

    float* pqp      = (float*)d_ws;                             // (2,B,128)
    float* energies = pqp + 2 * BB * ATT_DIM;                   // (B,T)
    float* partP    = energies + BB * TT;                       // (2*NTILE,B,ENC)
    float* partS    = partP + (long)2 * NTILE * BB * ENC_DIM;   // (4*NTILE,B)

    k_pq   <<<dim3(BB, 2),     dim3(256), 0, stream>>>(query, Wq, pqp);
    k_fused<<<dim3(NTILE, BB), dim3(256), 0, stream>>>(awc, ck, Wloc, pm, pqp, v,
                                                       memory, energies, partP, partS);
    k_final<<<dim3(BB),        dim3(256), 0, stream>>>(energies, partP, partS, wts, ctx);
}

// Round 20
// 91.840 us; speedup vs baseline: 1.1988x; 1.0253x over previous
//
#include <hip/hip_runtime.h>
#include <hip/hip_bf16.h>

#define BB 128
#define TT 1024
#define ENC_DIM 512
#define QUERY_DIM 1024
#define ATT_DIM 128
#define ATT_FILTERS 32
#define ATT_KERNEL 31
#define TILE_T 64
#define NTILE (TT / TILE_T)   // 16

using f32x4 = __attribute__((ext_vector_type(4))) float;
using f32x2 = __attribute__((ext_vector_type(2))) float;

__device__ __forceinline__ float tanh_fast(float x) {
    float e = __expf(2.0f * x);
    return 1.0f - 2.0f * __builtin_amdgcn_rcpf(1.0f + e);
}

// K1: pq partials. grid (B, 2).
__global__ __launch_bounds__(256) void k_pq(const float* __restrict__ query,
                                            const float* __restrict__ Wq,
                                            float* __restrict__ pqp) {
    __shared__ float q[512];
    __shared__ float pp[128];
    int b = blockIdx.x, h = blockIdx.y;
    int tid = threadIdx.x, a = tid & 127, ks = tid >> 7;
    for (int i = tid; i < 512; i += 256) q[i] = query[b * QUERY_DIM + h * 512 + i];
    __syncthreads();
    const float* w  = Wq + (h * 512 + ks * 256) * ATT_DIM + a;
    const float* qs = q + ks * 256;
    float acc = 0.f;
#pragma unroll 16
    for (int k = 0; k < 256; ++k) acc += qs[k] * w[k * ATT_DIM];
    if (ks) pp[a] = acc;
    __syncthreads();
    if (!ks) pqp[(h * BB + b) * ATT_DIM + a] = acc + pp[a];
}

// K2: R16 + per-half partP slots (no sr reduction, no tail barriers).
// grid (NTILE, B). Phase B identical to R16 (register-neutral energies loop).
__global__ __launch_bounds__(256, 4) void k_fused(
    const float* __restrict__ aw,    // (B,T,2)
    const float* __restrict__ ck,    // (31,2,32)
    const float* __restrict__ Wloc,  // (32,128)
    const float* __restrict__ pm,    // (B,T,128)
    const float* __restrict__ pqp,   // (2,B,128)
    const float* __restrict__ v,     // (128)
    const float* __restrict__ mem,   // (B,T,ENC)
    float* __restrict__ energies,    // (B,T) ws
    float* __restrict__ partP,       // (2*NTILE,B,ENC) ws: per half-block
    float* __restrict__ partS)       // (NTILE,B) ws: chunk exp-sums
{
    __shared__ float s_aw[(TILE_T + 30) * 2];
    __shared__ float s_ck[ATT_KERNEL * 2 * ATT_FILTERS];
    __shared__ float s_f[TILE_T * ATT_FILTERS];
    __shared__ float s_e[TILE_T];
    __shared__ float s_w[TILE_T];

    int s = blockIdx.x, b = blockIdx.y;
    int t0 = s * TILE_T;
    int tid = threadIdx.x;

    // ---- stage conv weights + aw halo ----
    for (int i = tid; i < ATT_KERNEL * 2 * ATT_FILTERS; i += 256) s_ck[i] = ck[i];
    for (int i = tid; i < (TILE_T + 30) * 2; i += 256) {
        int ii = i >> 1, c = i & 1;
        int t = t0 - 15 + ii;
        s_aw[i] = (t >= 0 && t < TT) ? aw[(b * TT + t) * 2 + c] : 0.f;
    }
    __syncthreads();

    {   // conv: filter j per thread, weights register-cached
        int j = tid & 31;
        float wk0[ATT_KERNEL], wk1[ATT_KERNEL];
#pragma unroll
        for (int k = 0; k < ATT_KERNEL; ++k) {
            wk0[k] = s_ck[k * 64 + j];
            wk1[k] = s_ck[k * 64 + 32 + j];
        }
        for (int t = tid >> 5; t < TILE_T; t += 8) {
            float acc0 = 0.f, acc1 = 0.f;
#pragma unroll
            for (int k = 0; k < ATT_KERNEL; ++k) {
                float2 awp = *reinterpret_cast<const float2*>(&s_aw[(t + k) * 2]);
                acc0 += awp.x * wk0[k];
                acc1 += awp.y * wk1[k];
            }
            s_f[t * ATT_FILTERS + j] = acc0 + acc1;
        }
    }
    __syncthreads();

    {   // energies (identical to R16 — no extra live state)
        int w = tid >> 6, lane = tid & 63;
        int a = lane * 2;
        float2 wl[ATT_FILTERS];
#pragma unroll
        for (int j = 0; j < ATT_FILTERS; ++j)
            wl[j] = *reinterpret_cast<const float2*>(&Wloc[j * ATT_DIM + a]);
        float2 pqA = *reinterpret_cast<const float2*>(&pqp[b * ATT_DIM + a]);
        float2 pqB = *reinterpret_cast<const float2*>(&pqp[(BB + b) * ATT_DIM + a]);
        float pq0 = pqA.x + pqB.x, pq1 = pqA.y + pqB.y;
        float2 vv = *reinterpret_cast<const float2*>(&v[a]);
        const float* pmb = pm + ((long)(b * TT + t0)) * ATT_DIM + a;

        auto process = [&](int t, float2 c) {
            float x0 = pq0 + c.x;
            float x1 = pq1 + c.y;
            const float4* f4 = reinterpret_cast<const float4*>(&s_f[t * ATT_FILTERS]);
#pragma unroll
            for (int j4 = 0; j4 < ATT_FILTERS / 4; ++j4) {
                float4 f = f4[j4];
                x0 += f.x * wl[4 * j4].x     + f.y * wl[4 * j4 + 1].x
                    + f.z * wl[4 * j4 + 2].x + f.w * wl[4 * j4 + 3].x;
                x1 += f.x * wl[4 * j4].y     + f.y * wl[4 * j4 + 1].y
                    + f.z * wl[4 * j4 + 2].y + f.w * wl[4 * j4 + 3].y;
            }
            float e = tanh_fast(x0) * vv.x + tanh_fast(x1) * vv.y;
#pragma unroll
            for (int off = 32; off > 0; off >>= 1) e += __shfl_xor(e, off);
            if (lane == 0) {
                s_e[t] = e;
                energies[b * TT + t0 + t] = e;
            }
        };

#pragma unroll
        for (int g = 0; g < 4; ++g) {   // 4 rows in flight; 4 groups x 16 t = 64
            int tg = w + g * 16;
            float2 c0 = *reinterpret_cast<const float2*>(&pmb[(tg)      * ATT_DIM]);
            float2 c1 = *reinterpret_cast<const float2*>(&pmb[(tg + 4)  * ATT_DIM]);
            float2 c2 = *reinterpret_cast<const float2*>(&pmb[(tg + 8)  * ATT_DIM]);
            float2 c3 = *reinterpret_cast<const float2*>(&pmb[(tg + 12) * ATT_DIM]);
            process(tg, c0);
            process(tg + 4, c1);
            process(tg + 8, c2);
            process(tg + 12, c3);
        }
    }
    __syncthreads();

    // ---- Phase B: max-free chunk softmax (identical to R16) ----
    float ex = 0.f;
    if (tid < TILE_T) {
        ex = __expf(s_e[tid]);
        s_w[tid] = ex;
    }
    __syncthreads();
    if (tid < 64) {   // wave 0: parallel sum of the 64 chunk exps (from register)
        float ss = ex;
#pragma unroll
        for (int off = 32; off > 0; off >>= 1) ss += __shfl_xor(ss, off);
        if (tid == 0) partS[s * BB + b] = ss;
    }

    // ---- Phase C: NT stream; each half-block writes its own partP slot ----
    int p = tid >> 7, q = tid & 127;
    const f32x4* m4 = reinterpret_cast<const f32x4*>(mem + ((long)(b * TT + t0)) * ENC_DIM) + q;
    f32x4 acc = {0.f, 0.f, 0.f, 0.f};
#pragma unroll 16
    for (int t = p; t < TILE_T; t += 2) {
        float wt = s_w[t];
        f32x4 mv = __builtin_nontemporal_load(&m4[(long)t * (ENC_DIM / 4)]);
        acc += wt * mv;
    }
    reinterpret_cast<f32x4*>(partP)[((s * 2 + p) * BB + b) * (ENC_DIM / 4) + q] = acc;
}

// K3: combine partials -> ctx, wts. grid (B).
__global__ __launch_bounds__(256) void k_final(
    const float* __restrict__ energies, // (B,T)
    const float* __restrict__ partP,    // (2*NTILE,B,ENC)
    const float* __restrict__ partS,    // (NTILE,B)
    float* __restrict__ wts,            // (B,T) out
    float* __restrict__ ctx)            // (B,ENC) out
{
    int b = blockIdx.x;
    int tid = threadIdx.x;

    float S = 0.f;
#pragma unroll
    for (int i = 0; i < NTILE; ++i) S += partS[i * BB + b];
    float invS = 1.0f / S;

    {   // weights: 1024 per row, 4 per thread
        float4 e = reinterpret_cast<const float4*>(energies + b * TT)[tid];
        float4 w;
        w.x = __expf(e.x) * invS;
        w.y = __expf(e.y) * invS;
        w.z = __expf(e.z) * invS;
        w.w = __expf(e.w) * invS;
        reinterpret_cast<float4*>(wts + b * TT)[tid] = w;
    }
    {   // context: 512 per row, 2 per thread
        f32x2 acc2 = {0.f, 0.f};
#pragma unroll
        for (int i = 0; i < 2 * NTILE; ++i) {
            f32x2 pv = *reinterpret_cast<const f32x2*>(&partP[((long)(i * BB + b)) * ENC_DIM + 2 * tid]);
            acc2 += pv;
        }
        acc2 *= invS;
        *reinterpret_cast<f32x2*>(&ctx[b * ENC_DIM + 2 * tid]) = acc2;
    }
}

extern "C" void kernel_launch(void* const* d_in, const int* in_sizes, int n_in,
                              void* d_out, int out_size, void* d_ws, size_t ws_size,
                              hipStream_t stream) {
    const float* query  = (const float*)d_in[0];
    const float* memory = (const float*)d_in[1];
    const float* pm     = (const float*)d_in[2];
    const float* awc    = (const float*)d_in[3];
    const float* Wq     = (const float*)d_in[4];
    const float* ck     = (const float*)d_in[5];
    const float* Wloc   = (const float*)d_in[6];
    const float* v      = (const float*)d_in[7];

    float* out = (float*)d_out;
    float* ctx = out;                       // (B, ENC_DIM)
    float* wts = out + BB * ENC_DIM;        // (B, T)

    float* pqp      = (float*)d_ws;                             // (2,B,128)
    float* energies = pqp + 2 * BB * ATT_DIM;                   // (B,T)
    float* partP    = energies + BB * TT;                       // (2*NTILE,B,ENC)
    float* partS    = partP + (long)2 * NTILE * BB * ENC_DIM;   // (NTILE,B)

    k_pq   <<<dim3(BB, 2),     dim3(256), 0, stream>>>(query, Wq, pqp);
    k_fused<<<dim3(NTILE, BB), dim3(256), 0, stream>>>(awc, ck, Wloc, pm, pqp, v,
                                                       memory, energies, partP, partS);
    k_final<<<dim3(BB),        dim3(256), 0, stream>>>(energies, partP, partS, wts, ctx);
}

// Round 21
// 87.944 us; speedup vs baseline: 1.2520x; 1.0443x over previous
//
#include <hip/hip_runtime.h>
#include <hip/hip_bf16.h>

#define BB 128
#define TT 1024
#define ENC_DIM 512
#define QUERY_DIM 1024
#define ATT_DIM 128
#define ATT_FILTERS 32
#define ATT_KERNEL 31
#define TILE_T 64
#define NTILE (TT / TILE_T)   // 16

using f32x4 = __attribute__((ext_vector_type(4))) float;
using f32x2 = __attribute__((ext_vector_type(2))) float;

__device__ __forceinline__ float tanh_fast(float x) {
    float e = __expf(2.0f * x);
    return 1.0f - 2.0f * __builtin_amdgcn_rcpf(1.0f + e);
}

// K1: pq partials. grid (B, 2).
__global__ __launch_bounds__(256) void k_pq(const float* __restrict__ query,
                                            const float* __restrict__ Wq,
                                            float* __restrict__ pqp) {
    __shared__ float q[512];
    __shared__ float pp[128];
    int b = blockIdx.x, h = blockIdx.y;
    int tid = threadIdx.x, a = tid & 127, ks = tid >> 7;
    for (int i = tid; i < 512; i += 256) q[i] = query[b * QUERY_DIM + h * 512 + i];
    __syncthreads();
    const float* w  = Wq + (h * 512 + ks * 256) * ATT_DIM + a;
    const float* qs = q + ks * 256;
    float acc = 0.f;
#pragma unroll 16
    for (int k = 0; k < 256; ++k) acc += qs[k] * w[k * ATT_DIM];
    if (ks) pp[a] = acc;
    __syncthreads();
    if (!ks) pqp[(h * BB + b) * ATT_DIM + a] = acc + pp[a];
}

// K2: fused energies + max-free chunk softmax + context partials.
// grid (NTILE, B). (256,4): allocator lands at 64 VGPR = occupancy sweet spot.
__global__ __launch_bounds__(256, 4) void k_fused(
    const float* __restrict__ aw,    // (B,T,2)
    const float* __restrict__ ck,    // (31,2,32)
    const float* __restrict__ Wloc,  // (32,128)
    const float* __restrict__ pm,    // (B,T,128)
    const float* __restrict__ pqp,   // (2,B,128)
    const float* __restrict__ v,     // (128)
    const float* __restrict__ mem,   // (B,T,ENC)
    float* __restrict__ energies,    // (B,T) ws
    float* __restrict__ partP,       // (NTILE,B,ENC) ws, unnormalized exp-weighted
    float* __restrict__ partS)       // (NTILE,B) ws: chunk exp-sums
{
    __shared__ float s_aw[(TILE_T + 30) * 2];
    __shared__ float s_ck[ATT_KERNEL * 2 * ATT_FILTERS];
    __shared__ float s_f[TILE_T * ATT_FILTERS];
    __shared__ float s_e[TILE_T];
    __shared__ float s_w[TILE_T];
    __shared__ f32x4 sr[ENC_DIM / 4];

    int s = blockIdx.x, b = blockIdx.y;
    int t0 = s * TILE_T;
    int tid = threadIdx.x;

    // ---- Phase A: conv + energies ----
    for (int i = tid; i < ATT_KERNEL * 2 * ATT_FILTERS; i += 256) s_ck[i] = ck[i];
    for (int i = tid; i < (TILE_T + 30) * 2; i += 256) {
        int ii = i >> 1, c = i & 1;
        int t = t0 - 15 + ii;
        s_aw[i] = (t >= 0 && t < TT) ? aw[(b * TT + t) * 2 + c] : 0.f;
    }
    __syncthreads();

    {   // conv: filter j per thread, weights register-cached
        int j = tid & 31;
        float wk0[ATT_KERNEL], wk1[ATT_KERNEL];
#pragma unroll
        for (int k = 0; k < ATT_KERNEL; ++k) {
            wk0[k] = s_ck[k * 64 + j];
            wk1[k] = s_ck[k * 64 + 32 + j];
        }
        for (int t = tid >> 5; t < TILE_T; t += 8) {
            float acc0 = 0.f, acc1 = 0.f;
#pragma unroll
            for (int k = 0; k < ATT_KERNEL; ++k) {
                float2 awp = *reinterpret_cast<const float2*>(&s_aw[(t + k) * 2]);
                acc0 += awp.x * wk0[k];
                acc1 += awp.y * wk1[k];
            }
            s_f[t * ATT_FILTERS + j] = acc0 + acc1;
        }
    }
    __syncthreads();

    {
        int w = tid >> 6, lane = tid & 63;
        int a = lane * 2;
        float2 wl[ATT_FILTERS];
#pragma unroll
        for (int j = 0; j < ATT_FILTERS; ++j)
            wl[j] = *reinterpret_cast<const float2*>(&Wloc[j * ATT_DIM + a]);
        float2 pqA = *reinterpret_cast<const float2*>(&pqp[b * ATT_DIM + a]);
        float2 pqB = *reinterpret_cast<const float2*>(&pqp[(BB + b) * ATT_DIM + a]);
        float pq0 = pqA.x + pqB.x, pq1 = pqA.y + pqB.y;
        float2 vv = *reinterpret_cast<const float2*>(&v[a]);
        const float* pmb = pm + ((long)(b * TT + t0)) * ATT_DIM + a;

        auto process = [&](int t, float2 c) {
            float x0 = pq0 + c.x;
            float x1 = pq1 + c.y;
            const float4* f4 = reinterpret_cast<const float4*>(&s_f[t * ATT_FILTERS]);
#pragma unroll
            for (int j4 = 0; j4 < ATT_FILTERS / 4; ++j4) {
                float4 f = f4[j4];
                x0 += f.x * wl[4 * j4].x     + f.y * wl[4 * j4 + 1].x
                    + f.z * wl[4 * j4 + 2].x + f.w * wl[4 * j4 + 3].x;
                x1 += f.x * wl[4 * j4].y     + f.y * wl[4 * j4 + 1].y
                    + f.z * wl[4 * j4 + 2].y + f.w * wl[4 * j4 + 3].y;
            }
            float e = tanh_fast(x0) * vv.x + tanh_fast(x1) * vv.y;
#pragma unroll
            for (int off = 32; off > 0; off >>= 1) e += __shfl_xor(e, off);
            if (lane == 0) {
                s_e[t] = e;
                energies[b * TT + t0 + t] = e;
            }
        };

#pragma unroll
        for (int g = 0; g < 4; ++g) {   // 4 rows in flight; 4 groups x 16 t = 64
            int tg = w + g * 16;
            float2 c0 = *reinterpret_cast<const float2*>(&pmb[(tg)      * ATT_DIM]);
            float2 c1 = *reinterpret_cast<const float2*>(&pmb[(tg + 4)  * ATT_DIM]);
            float2 c2 = *reinterpret_cast<const float2*>(&pmb[(tg + 8)  * ATT_DIM]);
            float2 c3 = *reinterpret_cast<const float2*>(&pmb[(tg + 12) * ATT_DIM]);
            process(tg, c0);
            process(tg + 4, c1);
            process(tg + 8, c2);
            process(tg + 12, c3);
        }
    }
    __syncthreads();

    // ---- Phase B: max-free chunk softmax (|e| <= ~9, exp is f32-safe) ----
    float ex = 0.f;
    if (tid < TILE_T) {
        ex = __expf(s_e[tid]);
        s_w[tid] = ex;
    }
    __syncthreads();
    if (tid < 64) {   // wave 0: parallel sum of the 64 chunk exps (from register)
        float ss = ex;
#pragma unroll
        for (int off = 32; off > 0; off >>= 1) ss += __shfl_xor(ss, off);
        if (tid == 0) partS[s * BB + b] = ss;
    }

    // ---- Phase C: stream this block's memory chunk (NT loads, permanent) ----
    int p = tid >> 7, q = tid & 127;
    const f32x4* m4 = reinterpret_cast<const f32x4*>(mem + ((long)(b * TT + t0)) * ENC_DIM) + q;
    f32x4 acc = {0.f, 0.f, 0.f, 0.f};
#pragma unroll 16
    for (int t = p; t < TILE_T; t += 2) {
        float wt = s_w[t];
        f32x4 mv = __builtin_nontemporal_load(&m4[(long)t * (ENC_DIM / 4)]);
        acc += wt * mv;
    }
    __syncthreads();
    if (p == 1) sr[q] = acc;
    __syncthreads();
    if (p == 0) {
        acc += sr[q];
        reinterpret_cast<f32x4*>(partP)[(s * BB + b) * (ENC_DIM / 4) + q] = acc;
    }
}

// K3: combine partials -> ctx, wts. grid (B). Single pass: S = sum of partS.
__global__ __launch_bounds__(256) void k_final(
    const float* __restrict__ energies, // (B,T)
    const float* __restrict__ partP,    // (NTILE,B,ENC)
    const float* __restrict__ partS,    // (NTILE,B)
    float* __restrict__ wts,            // (B,T) out
    float* __restrict__ ctx)            // (B,ENC) out
{
    int b = blockIdx.x;
    int tid = threadIdx.x;

    float S = 0.f;
#pragma unroll
    for (int i = 0; i < NTILE; ++i) S += partS[i * BB + b];
    float invS = 1.0f / S;

    {   // weights: 1024 per row, 4 per thread
        float4 e = reinterpret_cast<const float4*>(energies + b * TT)[tid];
        float4 w;
        w.x = __expf(e.x) * invS;
        w.y = __expf(e.y) * invS;
        w.z = __expf(e.z) * invS;
        w.w = __expf(e.w) * invS;
        reinterpret_cast<float4*>(wts + b * TT)[tid] = w;
    }
    {   // context: 512 per row, 2 per thread
        f32x2 acc2 = {0.f, 0.f};
#pragma unroll
        for (int i = 0; i < NTILE; ++i) {
            f32x2 pv = *reinterpret_cast<const f32x2*>(&partP[((long)(i * BB + b)) * ENC_DIM + 2 * tid]);
            acc2 += pv;
        }
        acc2 *= invS;
        *reinterpret_cast<f32x2*>(&ctx[b * ENC_DIM + 2 * tid]) = acc2;
    }
}

extern "C" void kernel_launch(void* const* d_in, const int* in_sizes, int n_in,
                              void* d_out, int out_size, void* d_ws, size_t ws_size,
                              hipStream_t stream) {
    const float* query  = (const float*)d_in[0];
    const float* memory = (const float*)d_in[1];
    const float* pm     = (const float*)d_in[2];
    const float* awc    = (const float*)d_in[3];
    const float* Wq     = (const float*)d_in[4];
    const float* ck     = (const float*)d_in[5];
    const float* Wloc   = (const float*)d_in[6];
    const float* v      = (const float*)d_in[7];

    float* out = (float*)d_out;
    float* ctx = out;                       // (B, ENC_DIM)
    float* wts = out + BB * ENC_DIM;        // (B, T)

    float* pqp      = (float*)d_ws;                        // (2,B,128)
    float* energies = pqp + 2 * BB * ATT_DIM;              // (B,T)
    float* partP    = energies + BB * TT;                  // (NTILE,B,ENC)
    float* partS    = partP + (long)NTILE * BB * ENC_DIM;  // (NTILE,B)

    k_pq   <<<dim3(BB, 2),     dim3(256), 0, stream>>>(query, Wq, pqp);
    k_fused<<<dim3(NTILE, BB), dim3(256), 0, stream>>>(awc, ck, Wloc, pm, pqp, v,
                                                       memory, energies, partP, partS);
    k_final<<<dim3(BB),        dim3(256), 0, stream>>>(energies, partP, partS, wts, ctx);
}